// Round 11
// baseline (377.942 us; speedup 1.0000x reference)
//
#include <hip/hip_runtime.h>
#include <hip/hip_bf16.h>

typedef __attribute__((ext_vector_type(8))) _Float16 half8;
typedef __attribute__((ext_vector_type(4))) float f32x4;
typedef __attribute__((ext_vector_type(4))) float float4v;

#define NPB 256        // nodes per bucket (dst >> 8)
#define PBLK 256       // partition blocks
#define SCAN_TILE 1024

// ---------------- phase 1: per-(block,bucket) histogram ----------------
__global__ __launch_bounds__(256) void p1_hist(const int* __restrict__ dst,
                                               int* __restrict__ MT, int E, int NB, int chunk) {
    __shared__ int h[512];
    int t = threadIdx.x, p = blockIdx.x;
    for (int i = t; i < NB; i += 256) h[i] = 0;
    __syncthreads();
    int beg = p * chunk, end = min(beg + chunk, E);
    for (int e = beg + t; e < end; e += 256) atomicAdd(&h[dst[e] >> 8], 1);
    __syncthreads();
    for (int b = t; b < NB; b += 256) MT[b * PBLK + p] = h[b];
}

// ---------------- device-wide exclusive scan (1024-elem tiles) ----------------
__global__ __launch_bounds__(256) void scanA_kernel(const int* __restrict__ in,
                                                    int* __restrict__ out,
                                                    int* __restrict__ blocksums, int n) {
    __shared__ int sums[256];
    int t = threadIdx.x;
    int base = blockIdx.x * SCAN_TILE + t * 4;
    int v0 = (base + 0 < n) ? in[base + 0] : 0;
    int v1 = (base + 1 < n) ? in[base + 1] : 0;
    int v2 = (base + 2 < n) ? in[base + 2] : 0;
    int v3 = (base + 3 < n) ? in[base + 3] : 0;
    sums[t] = v0 + v1 + v2 + v3;
    __syncthreads();
    for (int off = 1; off < 256; off <<= 1) {
        int add = (t >= off) ? sums[t - off] : 0;
        __syncthreads();
        sums[t] += add;
        __syncthreads();
    }
    int run = (t == 0) ? 0 : sums[t - 1];
    if (base + 0 < n) out[base + 0] = run; run += v0;
    if (base + 1 < n) out[base + 1] = run; run += v1;
    if (base + 2 < n) out[base + 2] = run; run += v2;
    if (base + 3 < n) out[base + 3] = run;
    if (t == 255) blocksums[blockIdx.x] = sums[255];
}

__global__ __launch_bounds__(256) void scanB_kernel(int* __restrict__ blocksums, int nb) {
    __shared__ int sums[256];
    int t = threadIdx.x;
    sums[t] = (t < nb) ? blocksums[t] : 0;
    __syncthreads();
    for (int off = 1; off < 256; off <<= 1) {
        int add = (t >= off) ? sums[t - off] : 0;
        __syncthreads();
        sums[t] += add;
        __syncthreads();
    }
    if (t < nb) blocksums[t] = (t == 0) ? 0 : sums[t - 1];
}

__global__ __launch_bounds__(256) void scanC_kernel(int* __restrict__ data,
                                                    const int* __restrict__ blocksums, int n) {
    int i = blockIdx.x * 256 + threadIdx.x;
    if (i < n) data[i] += blocksums[i / SCAN_TILE];
}

// ---------------- phase 2: partition edges into buckets (LDS cursors only) ----------------
__global__ __launch_bounds__(256) void p2_part(const int* __restrict__ src,
                                               const int* __restrict__ dst,
                                               const float* __restrict__ ew,
                                               const int* __restrict__ MTs,
                                               int* __restrict__ pp, float* __restrict__ pw,
                                               int E, int NB, int chunk) {
    __shared__ int cur[512];
    int t = threadIdx.x, p = blockIdx.x;
    for (int b = t; b < NB; b += 256) cur[b] = MTs[b * PBLK + p];
    __syncthreads();
    int beg = p * chunk, end = min(beg + chunk, E);
    for (int e = beg + t; e < end; e += 256) {
        int d = dst[e];
        int b = d >> 8;
        int pos = atomicAdd(&cur[b], 1);
        pp[pos] = src[e] | ((d & 255) << 20);   // src < 2^20, dlocal in [0,256)
        pw[pos] = ew[e];
    }
}

// ---------------- phase 3: per-bucket exact CSR + degree + dinv ----------------
__global__ __launch_bounds__(256) void p3_bucket(const int* __restrict__ pp,
                                                 const float* __restrict__ pw,
                                                 const int* __restrict__ MTs,
                                                 int* __restrict__ srcs,
                                                 float* __restrict__ ews,
                                                 int* __restrict__ rowptr,
                                                 float* __restrict__ dinv,
                                                 int E, int N, int NB) {
    __shared__ int cnt[256];
    __shared__ float wd[256];
    __shared__ int ls[256];
    __shared__ int cur[256];
    int t = threadIdx.x, b = blockIdx.x;
    int beg = MTs[b * PBLK];
    int end = (b == NB - 1) ? E : MTs[(b + 1) * PBLK];
    cnt[t] = 0;
    wd[t] = 0.0f;
    __syncthreads();
    for (int e = beg + t; e < end; e += 256) {
        int v = pp[e];
        int dl = v >> 20;
        atomicAdd(&cnt[dl], 1);
        atomicAdd(&wd[dl], pw[e]);
    }
    __syncthreads();
    ls[t] = cnt[t];
    __syncthreads();
    for (int off = 1; off < 256; off <<= 1) {
        int add = (t >= off) ? ls[t - off] : 0;
        __syncthreads();
        ls[t] += add;
        __syncthreads();
    }
    int excl = (t == 0) ? 0 : ls[t - 1];
    int node = b * NPB + t;
    if (node < N) {
        rowptr[node] = beg + excl;
        dinv[node] = rsqrtf(1.0f + wd[t]);   // +1 = self-loop weight
    }
    cur[t] = beg + excl;
    if (b == NB - 1 && t == 0) rowptr[N] = E;
    __syncthreads();
    for (int e = beg + t; e < end; e += 256) {
        int v = pp[e];
        int dl = v >> 20;
        int pos = atomicAdd(&cur[dl], 1);
        srcs[pos] = v & 0xFFFFF;
        ews[pos] = pw[e];
    }
}

// ---------------- wconv: WT16[c][k] = fp16(W[k][c]) for both layers ----------------
__global__ __launch_bounds__(256) void wconv(const float* __restrict__ W1,
                                             const float* __restrict__ W2,
                                             _Float16* __restrict__ WT1,
                                             _Float16* __restrict__ WT2) {
    int i = blockIdx.x * 256 + threadIdx.x;   // 16384 elems, i = c*128+k
    if (i >= 128 * 128) return;
    int c = i >> 7, k = i & 127;
    WT1[i] = (_Float16)W1[(size_t)k * 128 + c];
    WT2[i] = (_Float16)W2[(size_t)k * 128 + c];
}

// ---------------- split_scale: xs = fp16(dinv .* x) ----------------
__global__ __launch_bounds__(256) void split_scale(const float* __restrict__ x,
                                                   const float* __restrict__ dinv,
                                                   _Float16* __restrict__ xs,
                                                   int nquad) {   // nquad = N*32 float4s
    int i = blockIdx.x * 256 + threadIdx.x;
    if (i >= nquad) return;
    float4v v = ((const float4v*)x)[i];
    float s = dinv[i >> 5];   // 32 float4s per 128-col row
    union { uint2 u; _Float16 h[4]; } o;
    o.h[0] = (_Float16)(s * v[0]);
    o.h[1] = (_Float16)(s * v[1]);
    o.h[2] = (_Float16)(s * v[2]);
    o.h[3] = (_Float16)(s * v[3]);
    ((uint2*)xs)[i] = o.u;
}

// ---------------- fused agg + GEMM ----------------
// Per wave: aggregate 16 nodes (t = dinv.*(sum ew*F[src] + F[self]), fp16) into a
// private LDS tile, then immediately MFMA the 16x128 panel against Wt (fp16,
// transposed [c][k], L2-resident global — no LDS staging, no barriers).
// mode 0: outb = fp16(dinv .* relu(t@W+b));  mode 1: outf = relu(t@W+b)
#define TPITCH 68   // uints per t-row (16B-aligned, bank-skewed)

__global__ __launch_bounds__(256) void fused_agg_gemm(const _Float16* __restrict__ F,
                                                      const int* __restrict__ rowptr,
                                                      const int* __restrict__ srcs,
                                                      const float* __restrict__ ews,
                                                      const float* __restrict__ dinv,
                                                      const _Float16* __restrict__ Wt,
                                                      const float* __restrict__ bias,
                                                      _Float16* __restrict__ outb,
                                                      float* __restrict__ outf,
                                                      int n, int mode) {
    __shared__ unsigned sT[4][16 * TPITCH];   // per-wave t tiles (17 KB)

    const unsigned* Fu = (const unsigned*)F;
    const int t = threadIdx.x;
    const int wave = t >> 6;
    const int lane = t & 63;
    unsigned* myT = sT[wave];

    const int base = (blockIdx.x * 4 + wave) * 16;

    // ---- phase 1: aggregate 16 nodes (all wave-uniform control flow) ----
    for (int r = 0; r < 16; ++r) {
        int node = base + r;
        if (node < n) {
            int beg = rowptr[node];
            int end = rowptr[node + 1];
            float di = dinv[node];

            union { unsigned u; _Float16 h[2]; } cv;
            cv.u = Fu[(size_t)node * 64 + lane];
            float accx = (float)cv.h[0];
            float accy = (float)cv.h[1];

            int e = beg;
            for (; e + 8 <= end; e += 8) {
                int s_[8];
                float w_[8];
                unsigned v_[8];
#pragma unroll
                for (int j = 0; j < 8; ++j) s_[j] = srcs[e + j];
#pragma unroll
                for (int j = 0; j < 8; ++j) w_[j] = ews[e + j];
#pragma unroll
                for (int j = 0; j < 8; ++j) v_[j] = Fu[(size_t)s_[j] * 64 + lane];
#pragma unroll
                for (int j = 0; j < 8; ++j) {
                    cv.u = v_[j];
                    accx += w_[j] * (float)cv.h[0];
                    accy += w_[j] * (float)cv.h[1];
                }
            }
            for (; e < end; ++e) {
                int s = srcs[e];
                float w = ews[e];
                cv.u = Fu[(size_t)s * 64 + lane];
                accx += w * (float)cv.h[0];
                accy += w * (float)cv.h[1];
            }

            union { unsigned u; _Float16 h[2]; } o;
            o.h[0] = (_Float16)(di * accx);
            o.h[1] = (_Float16)(di * accy);
            myT[r * TPITCH + lane] = o.u;
        } else {
            myT[r * TPITCH + lane] = 0;
        }
    }
    // (same-wave ds_write -> ds_read: compiler inserts lgkmcnt wait; no barrier needed)

    // ---- phase 2: 16x128 MFMA panel; B-fragments direct from L2-resident Wt ----
    const int fr = lane & 15;
    const int kq = lane >> 4;

    f32x4 acc[8];
#pragma unroll
    for (int fc = 0; fc < 8; ++fc) acc[fc] = (f32x4){0.f, 0.f, 0.f, 0.f};

#pragma unroll
    for (int ks = 0; ks < 4; ++ks) {
        half8 a = *(half8*)&myT[fr * TPITCH + ks * 16 + kq * 4];
        const _Float16* wp = Wt + ks * 32 + kq * 8;
#pragma unroll
        for (int fc = 0; fc < 8; ++fc) {
            half8 b = *(const half8*)(wp + (size_t)(fc * 16 + fr) * 128);
            acc[fc] = __builtin_amdgcn_mfma_f32_16x16x32_f16(a, b, acc[fc], 0, 0, 0);
        }
    }

    // ---- epilogue ----
    float bv[8];
#pragma unroll
    for (int fc = 0; fc < 8; ++fc) bv[fc] = bias[fc * 16 + fr];

    int rb = base + kq * 4;
    if (mode == 0) {
#pragma unroll
        for (int r = 0; r < 4; ++r) {
            int grow = rb + r;
            if (grow < n) {
                float s = dinv[grow];
#pragma unroll
                for (int fc = 0; fc < 8; ++fc) {
                    float v = fmaxf(acc[fc][r] + bv[fc], 0.0f);
                    outb[(size_t)grow * 128 + fc * 16 + fr] = (_Float16)(s * v);
                }
            }
        }
    } else {
#pragma unroll
        for (int r = 0; r < 4; ++r) {
            int grow = rb + r;
            if (grow < n) {
#pragma unroll
                for (int fc = 0; fc < 8; ++fc) {
                    outf[(size_t)grow * 128 + fc * 16 + fr] = fmaxf(acc[fc][r] + bv[fc], 0.0f);
                }
            }
        }
    }
}

// ---------------- launcher ----------------

extern "C" void kernel_launch(void* const* d_in, const int* in_sizes, int n_in,
                              void* d_out, int out_size, void* d_ws, size_t ws_size,
                              hipStream_t stream) {
    const float* x  = (const float*)d_in[0];
    const int*   ei = (const int*)d_in[1];
    const float* ew = (const float*)d_in[2];
    const float* W1 = (const float*)d_in[3];
    const float* b1 = (const float*)d_in[4];
    const float* W2 = (const float*)d_in[5];
    const float* b2 = (const float*)d_in[6];
    float* out = (float*)d_out;

    const int N = in_sizes[0] / 128;
    const int E = in_sizes[2];
    const int* src = ei;
    const int* dst = ei + E;

    const int NB = (N + NPB - 1) / NPB;        // buckets (391 for N=100k)
    const int L  = NB * PBLK;                  // count-matrix length
    const int chunk = (E + PBLK - 1) / PBLK;

    // workspace layout
    _Float16* gat  = (_Float16*)d_ws;                     // N*128 fp16 (gather features L1)
    _Float16* gat2 = gat + (size_t)N * 128;               // N*128 fp16 (gather features L2)
    int*   srcs   = (int*)(gat2 + (size_t)N * 128);       // E
    float* ews    = (float*)(srcs + E);        // E
    int*   rowptr = (int*)(ews + E);           // N+1
    float* dinv   = (float*)(rowptr + N + 1);  // N
    int*   MT     = (int*)(dinv + N);          // L
    int*   MTs    = MT + L;                    // L
    int*   bsums  = MTs + L;                   // ceil(L/1024)
    _Float16* WT1 = (_Float16*)(bsums + (L + SCAN_TILE - 1) / SCAN_TILE);  // 16384
    _Float16* WT2 = WT1 + 128 * 128;                                        // 16384
    int*   pp     = (int*)gat;                 // alias (E ints, dead before gat written)
    float* pw     = (float*)gat2;              // alias (E floats, dead before gat2 written)

    const int nb_scan = (L + SCAN_TILE - 1) / SCAN_TILE;
    const int fblocks = (N + 63) / 64;

    hipLaunchKernelGGL(p1_hist, dim3(PBLK), dim3(256), 0, stream, dst, MT, E, NB, chunk);
    hipLaunchKernelGGL(scanA_kernel, dim3(nb_scan), dim3(256), 0, stream, MT, MTs, bsums, L);
    hipLaunchKernelGGL(scanB_kernel, dim3(1), dim3(256), 0, stream, bsums, nb_scan);
    hipLaunchKernelGGL(scanC_kernel, dim3((L + 255) / 256), dim3(256), 0, stream, MTs, bsums, L);
    hipLaunchKernelGGL(p2_part, dim3(PBLK), dim3(256), 0, stream, src, dst, ew, MTs, pp, pw, E, NB, chunk);
    hipLaunchKernelGGL(p3_bucket, dim3(NB), dim3(256), 0, stream, pp, pw, MTs, srcs, ews, rowptr, dinv, E, N, NB);
    hipLaunchKernelGGL(wconv, dim3(64), dim3(256), 0, stream, W1, W2, WT1, WT2);

    // gat = fp16(dinv .* x)
    hipLaunchKernelGGL(split_scale, dim3((N * 32 + 255) / 256), dim3(256), 0, stream,
                       x, dinv, gat, N * 32);

    // layer 1 fused: gat2 = fp16(dinv .* relu( (dinv.*agg(gat)) @ W1 + b1 ))
    hipLaunchKernelGGL(fused_agg_gemm, dim3(fblocks), dim3(256), 0, stream,
                       gat, rowptr, srcs, ews, dinv, WT1, b1, gat2, (float*)nullptr, N, 0);

    // layer 2 fused: out = relu( (dinv.*agg(gat2)) @ W2 + b2 )
    hipLaunchKernelGGL(fused_agg_gemm, dim3(fblocks), dim3(256), 0, stream,
                       gat2, rowptr, srcs, ews, dinv, WT2, b2, (_Float16*)nullptr, out, N, 1);
}

// Round 12
// 267.710 us; speedup vs baseline: 1.4118x; 1.4118x over previous
//
#include <hip/hip_runtime.h>
#include <hip/hip_bf16.h>

typedef __attribute__((ext_vector_type(8))) _Float16 half8;
typedef __attribute__((ext_vector_type(4))) float f32x4;
typedef __attribute__((ext_vector_type(4))) float float4v;

#define NPB 256        // nodes per bucket (dst >> 8)
#define PBLK 256       // partition blocks
#define SCAN_TILE 1024

// ---------------- phase 1: per-(block,bucket) histogram ----------------
__global__ __launch_bounds__(256) void p1_hist(const int* __restrict__ dst,
                                               int* __restrict__ MT, int E, int NB, int chunk) {
    __shared__ int h[512];
    int t = threadIdx.x, p = blockIdx.x;
    for (int i = t; i < NB; i += 256) h[i] = 0;
    __syncthreads();
    int beg = p * chunk, end = min(beg + chunk, E);
    for (int e = beg + t; e < end; e += 256) atomicAdd(&h[dst[e] >> 8], 1);
    __syncthreads();
    for (int b = t; b < NB; b += 256) MT[b * PBLK + p] = h[b];
}

// ---------------- device-wide exclusive scan (1024-elem tiles) ----------------
__global__ __launch_bounds__(256) void scanA_kernel(const int* __restrict__ in,
                                                    int* __restrict__ out,
                                                    int* __restrict__ blocksums, int n) {
    __shared__ int sums[256];
    int t = threadIdx.x;
    int base = blockIdx.x * SCAN_TILE + t * 4;
    int v0 = (base + 0 < n) ? in[base + 0] : 0;
    int v1 = (base + 1 < n) ? in[base + 1] : 0;
    int v2 = (base + 2 < n) ? in[base + 2] : 0;
    int v3 = (base + 3 < n) ? in[base + 3] : 0;
    sums[t] = v0 + v1 + v2 + v3;
    __syncthreads();
    for (int off = 1; off < 256; off <<= 1) {
        int add = (t >= off) ? sums[t - off] : 0;
        __syncthreads();
        sums[t] += add;
        __syncthreads();
    }
    int run = (t == 0) ? 0 : sums[t - 1];
    if (base + 0 < n) out[base + 0] = run; run += v0;
    if (base + 1 < n) out[base + 1] = run; run += v1;
    if (base + 2 < n) out[base + 2] = run; run += v2;
    if (base + 3 < n) out[base + 3] = run;
    if (t == 255) blocksums[blockIdx.x] = sums[255];
}

__global__ __launch_bounds__(256) void scanB_kernel(int* __restrict__ blocksums, int nb) {
    __shared__ int sums[256];
    int t = threadIdx.x;
    sums[t] = (t < nb) ? blocksums[t] : 0;
    __syncthreads();
    for (int off = 1; off < 256; off <<= 1) {
        int add = (t >= off) ? sums[t - off] : 0;
        __syncthreads();
        sums[t] += add;
        __syncthreads();
    }
    if (t < nb) blocksums[t] = (t == 0) ? 0 : sums[t - 1];
}

__global__ __launch_bounds__(256) void scanC_kernel(int* __restrict__ data,
                                                    const int* __restrict__ blocksums, int n) {
    int i = blockIdx.x * 256 + threadIdx.x;
    if (i < n) data[i] += blocksums[i / SCAN_TILE];
}

// ---------------- phase 2: partition edges into buckets (LDS cursors only) ----------------
__global__ __launch_bounds__(256) void p2_part(const int* __restrict__ src,
                                               const int* __restrict__ dst,
                                               const float* __restrict__ ew,
                                               const int* __restrict__ MTs,
                                               int* __restrict__ pp, float* __restrict__ pw,
                                               int E, int NB, int chunk) {
    __shared__ int cur[512];
    int t = threadIdx.x, p = blockIdx.x;
    for (int b = t; b < NB; b += 256) cur[b] = MTs[b * PBLK + p];
    __syncthreads();
    int beg = p * chunk, end = min(beg + chunk, E);
    for (int e = beg + t; e < end; e += 256) {
        int d = dst[e];
        int b = d >> 8;
        int pos = atomicAdd(&cur[b], 1);
        pp[pos] = src[e] | ((d & 255) << 20);   // src < 2^20, dlocal in [0,256)
        pw[pos] = ew[e];
    }
}

// ---------------- phase 3: per-bucket exact CSR + degree + dinv ----------------
__global__ __launch_bounds__(256) void p3_bucket(const int* __restrict__ pp,
                                                 const float* __restrict__ pw,
                                                 const int* __restrict__ MTs,
                                                 int* __restrict__ srcs,
                                                 float* __restrict__ ews,
                                                 int* __restrict__ rowptr,
                                                 float* __restrict__ dinv,
                                                 int E, int N, int NB) {
    __shared__ int cnt[256];
    __shared__ float wd[256];
    __shared__ int ls[256];
    __shared__ int cur[256];
    int t = threadIdx.x, b = blockIdx.x;
    int beg = MTs[b * PBLK];
    int end = (b == NB - 1) ? E : MTs[(b + 1) * PBLK];
    cnt[t] = 0;
    wd[t] = 0.0f;
    __syncthreads();
    for (int e = beg + t; e < end; e += 256) {
        int v = pp[e];
        int dl = v >> 20;
        atomicAdd(&cnt[dl], 1);
        atomicAdd(&wd[dl], pw[e]);
    }
    __syncthreads();
    ls[t] = cnt[t];
    __syncthreads();
    for (int off = 1; off < 256; off <<= 1) {
        int add = (t >= off) ? ls[t - off] : 0;
        __syncthreads();
        ls[t] += add;
        __syncthreads();
    }
    int excl = (t == 0) ? 0 : ls[t - 1];
    int node = b * NPB + t;
    if (node < N) {
        rowptr[node] = beg + excl;
        dinv[node] = rsqrtf(1.0f + wd[t]);   // +1 = self-loop weight
    }
    cur[t] = beg + excl;
    if (b == NB - 1 && t == 0) rowptr[N] = E;
    __syncthreads();
    for (int e = beg + t; e < end; e += 256) {
        int v = pp[e];
        int dl = v >> 20;
        int pos = atomicAdd(&cur[dl], 1);
        srcs[pos] = v & 0xFFFFF;
        ews[pos] = pw[e];
    }
}

// ---------------- wconv: WT16[c][k] = fp16(W[k][c]) for both layers ----------------
__global__ __launch_bounds__(256) void wconv(const float* __restrict__ W1,
                                             const float* __restrict__ W2,
                                             _Float16* __restrict__ WT1,
                                             _Float16* __restrict__ WT2) {
    int i = blockIdx.x * 256 + threadIdx.x;   // 16384 elems, i = c*128+k
    if (i >= 128 * 128) return;
    int c = i >> 7, k = i & 127;
    WT1[i] = (_Float16)W1[(size_t)k * 128 + c];
    WT2[i] = (_Float16)W2[(size_t)k * 128 + c];
}

// ---------------- split_scale: xs = fp16(dinv .* x) ----------------
__global__ __launch_bounds__(256) void split_scale(const float* __restrict__ x,
                                                   const float* __restrict__ dinv,
                                                   _Float16* __restrict__ xs,
                                                   int nquad) {   // nquad = N*32 float4s
    int i = blockIdx.x * 256 + threadIdx.x;
    if (i >= nquad) return;
    float4v v = ((const float4v*)x)[i];
    float s = dinv[i >> 5];   // 32 float4s per 128-col row
    union { uint2 u; _Float16 h[4]; } o;
    o.h[0] = (_Float16)(s * v[0]);
    o.h[1] = (_Float16)(s * v[1]);
    o.h[2] = (_Float16)(s * v[2]);
    o.h[3] = (_Float16)(s * v[3]);
    ((uint2*)xs)[i] = o.u;
}

// ---------------- aggregation: t = fp16(dinv.*(sum ew*F[src] + F[self])) ----------------
// F is pre-scaled fp16 (dinv.*X or dinv.*H). One wave per node, lane = cols 2l,2l+1.
__global__ __launch_bounds__(256) void agg_kernel(const _Float16* __restrict__ F,
                                                  const int* __restrict__ rowptr,
                                                  const int* __restrict__ srcs,
                                                  const float* __restrict__ ews,
                                                  const float* __restrict__ dinv,
                                                  unsigned* __restrict__ ttU, int n) {
    const unsigned* Fu = (const unsigned*)F;   // one uint = 2 fp16 cols
    int wid  = (blockIdx.x * 256 + threadIdx.x) >> 6;
    int lane = threadIdx.x & 63;
    int node = __builtin_amdgcn_readfirstlane(wid);
    if (node >= n) return;

    int beg = rowptr[node];
    int end = rowptr[node + 1];
    float di = dinv[node];

    union { unsigned u; _Float16 h[2]; } cv;
    cv.u = Fu[(size_t)node * 64 + lane];
    float accx = (float)cv.h[0];
    float accy = (float)cv.h[1];

    int e = beg;
    for (; e + 8 <= end; e += 8) {
        int s_[8];
        float w_[8];
        unsigned v_[8];
#pragma unroll
        for (int j = 0; j < 8; ++j) s_[j] = srcs[e + j];
#pragma unroll
        for (int j = 0; j < 8; ++j) w_[j] = ews[e + j];
#pragma unroll
        for (int j = 0; j < 8; ++j) v_[j] = Fu[(size_t)s_[j] * 64 + lane];
#pragma unroll
        for (int j = 0; j < 8; ++j) {
            cv.u = v_[j];
            accx += w_[j] * (float)cv.h[0];
            accy += w_[j] * (float)cv.h[1];
        }
    }
    for (; e < end; ++e) {
        int s = srcs[e];
        float w = ews[e];
        cv.u = Fu[(size_t)s * 64 + lane];
        accx += w * (float)cv.h[0];
        accy += w * (float)cv.h[1];
    }

    union { unsigned u; _Float16 h[2]; } o;
    o.h[0] = (_Float16)(di * accx);
    o.h[1] = (_Float16)(di * accy);
    ttU[(size_t)node * 64 + lane] = o.u;
}

// ---------------- MFMA GEMM (fp16, staging-free): out = relu(A @ W + b) ----------------
// A fp16 single plane; B-fragments read DIRECTLY from pre-transposed fp16 Wt
// (32 KB, L1/L2-resident — no LDS, no barriers, no staging). 32-row wave panels,
// one per wave, A double-buffered.
// mode 0: outb = fp16(dinv .* relu(..));  mode 1: outf = relu(..)
__global__ __launch_bounds__(256, 4) void gemm_mfma(const _Float16* __restrict__ A,
                                                    const _Float16* __restrict__ Wt,
                                                    const float* __restrict__ bias,
                                                    const float* __restrict__ dinv,
                                                    _Float16* __restrict__ outb,
                                                    float* __restrict__ outf,
                                                    int nrows, int mode) {
    const int t = threadIdx.x;
    const int lane = t & 63;
    const int fr = lane & 15;      // frag row/col index
    const int kq = lane >> 4;      // 0..3 -> k sub-offset 8*kq

    const int wid = blockIdx.x * 4 + (t >> 6);      // one 32-row panel per wave
    const int npan = (nrows + 31) >> 5;
    if (wid >= npan) return;
    const int r0 = wid * 32;

    float bv[8];
#pragma unroll
    for (int fc = 0; fc < 8; ++fc) bv[fc] = bias[fc * 16 + fr];

    const half8 z8 = {0, 0, 0, 0, 0, 0, 0, 0};

#define LOADA(KS, AH)                                                         \
    {                                                                         \
        _Pragma("unroll")                                                     \
        for (int rf_ = 0; rf_ < 2; ++rf_) {                                   \
            int row_ = r0 + rf_ * 16 + fr;                                    \
            if (row_ < nrows) {                                               \
                AH[rf_] = *(const half8*)(A + (size_t)row_ * 128 + (KS) * 32 + kq * 8); \
            } else {                                                          \
                AH[rf_] = z8;                                                 \
            }                                                                 \
        }                                                                     \
    }

#define KSTEP(KS, AH)                                                         \
    {                                                                         \
        const _Float16* wp_ = Wt + (KS) * 32 + kq * 8;                        \
        _Pragma("unroll")                                                     \
        for (int fc_ = 0; fc_ < 8; ++fc_) {                                   \
            half8 b_ = *(const half8*)(wp_ + (size_t)(fc_ * 16 + fr) * 128);  \
            _Pragma("unroll")                                                 \
            for (int rf_ = 0; rf_ < 2; ++rf_) {                               \
                acc[rf_][fc_] = __builtin_amdgcn_mfma_f32_16x16x32_f16(       \
                    AH[rf_], b_, acc[rf_][fc_], 0, 0, 0);                     \
            }                                                                 \
        }                                                                     \
    }

    f32x4 acc[2][8];
#pragma unroll
    for (int rf = 0; rf < 2; ++rf)
#pragma unroll
        for (int fc = 0; fc < 8; ++fc) acc[rf][fc] = (f32x4){0.f, 0.f, 0.f, 0.f};

    half8 aA[2], aB[2];
    LOADA(0, aA);
    LOADA(1, aB);
    KSTEP(0, aA);
    LOADA(2, aA);
    KSTEP(1, aB);
    LOADA(3, aB);
    KSTEP(2, aA);
    KSTEP(3, aB);

#undef LOADA
#undef KSTEP

    // ---- epilogue: relu + bias; mode 0 -> dinv-scaled fp16, mode 1 -> fp32 ----
    if (mode == 0) {
#pragma unroll
        for (int rf = 0; rf < 2; ++rf) {
            int rb = r0 + rf * 16 + kq * 4;
#pragma unroll
            for (int r = 0; r < 4; ++r) {
                int grow = rb + r;
                if (grow < nrows) {
                    float s = dinv[grow];
#pragma unroll
                    for (int fc = 0; fc < 8; ++fc) {
                        float v = fmaxf(acc[rf][fc][r] + bv[fc], 0.0f);
                        outb[(size_t)grow * 128 + fc * 16 + fr] = (_Float16)(s * v);
                    }
                }
            }
        }
    } else {
#pragma unroll
        for (int rf = 0; rf < 2; ++rf) {
            int rb = r0 + rf * 16 + kq * 4;
#pragma unroll
            for (int r = 0; r < 4; ++r) {
                int grow = rb + r;
                if (grow < nrows) {
#pragma unroll
                    for (int fc = 0; fc < 8; ++fc) {
                        outf[(size_t)grow * 128 + fc * 16 + fr] =
                            fmaxf(acc[rf][fc][r] + bv[fc], 0.0f);
                    }
                }
            }
        }
    }
}

// ---------------- launcher ----------------

extern "C" void kernel_launch(void* const* d_in, const int* in_sizes, int n_in,
                              void* d_out, int out_size, void* d_ws, size_t ws_size,
                              hipStream_t stream) {
    const float* x  = (const float*)d_in[0];
    const int*   ei = (const int*)d_in[1];
    const float* ew = (const float*)d_in[2];
    const float* W1 = (const float*)d_in[3];
    const float* b1 = (const float*)d_in[4];
    const float* W2 = (const float*)d_in[5];
    const float* b2 = (const float*)d_in[6];
    float* out = (float*)d_out;

    const int N = in_sizes[0] / 128;
    const int E = in_sizes[2];
    const int* src = ei;
    const int* dst = ei + E;

    const int NB = (N + NPB - 1) / NPB;        // buckets (391 for N=100k)
    const int L  = NB * PBLK;                  // count-matrix length
    const int chunk = (E + PBLK - 1) / PBLK;

    // workspace layout
    _Float16* gat = (_Float16*)d_ws;                      // N*128 fp16 (gather features)
    _Float16* tt  = gat + (size_t)N * 128;                // N*128 fp16 (agg result t)
    int*   srcs   = (int*)(tt + (size_t)N * 128);         // E
    float* ews    = (float*)(srcs + E);        // E
    int*   rowptr = (int*)(ews + E);           // N+1
    float* dinv   = (float*)(rowptr + N + 1);  // N
    int*   MT     = (int*)(dinv + N);          // L
    int*   MTs    = MT + L;                    // L
    int*   bsums  = MTs + L;                   // ceil(L/1024)
    _Float16* WT1 = (_Float16*)(bsums + (L + SCAN_TILE - 1) / SCAN_TILE);  // 16384
    _Float16* WT2 = WT1 + 128 * 128;                                        // 16384
    int*   pp     = (int*)gat;                 // alias (E ints, dead before gat written)
    float* pw     = (float*)tt;                // alias (E floats, dead before tt written)

    const int nb_scan = (L + SCAN_TILE - 1) / SCAN_TILE;
    const int npan = (N + 31) / 32;
    const int gblocks = (npan + 3) / 4;

    hipLaunchKernelGGL(p1_hist, dim3(PBLK), dim3(256), 0, stream, dst, MT, E, NB, chunk);
    hipLaunchKernelGGL(scanA_kernel, dim3(nb_scan), dim3(256), 0, stream, MT, MTs, bsums, L);
    hipLaunchKernelGGL(scanB_kernel, dim3(1), dim3(256), 0, stream, bsums, nb_scan);
    hipLaunchKernelGGL(scanC_kernel, dim3((L + 255) / 256), dim3(256), 0, stream, MTs, bsums, L);
    hipLaunchKernelGGL(p2_part, dim3(PBLK), dim3(256), 0, stream, src, dst, ew, MTs, pp, pw, E, NB, chunk);
    hipLaunchKernelGGL(p3_bucket, dim3(NB), dim3(256), 0, stream, pp, pw, MTs, srcs, ews, rowptr, dinv, E, N, NB);
    hipLaunchKernelGGL(wconv, dim3(64), dim3(256), 0, stream, W1, W2, WT1, WT2);

    // gat = fp16(dinv .* x)
    hipLaunchKernelGGL(split_scale, dim3((N * 32 + 255) / 256), dim3(256), 0, stream,
                       x, dinv, gat, N * 32);

    // layer 1: tt = fp16(dinv.*agg(gat)) ; gat = fp16(dinv.*relu(tt@W1+b1))
    hipLaunchKernelGGL(agg_kernel, dim3((N + 3) / 4), dim3(256), 0, stream,
                       gat, rowptr, srcs, ews, dinv, (unsigned*)tt, N);
    hipLaunchKernelGGL(gemm_mfma, dim3(gblocks), dim3(256), 0, stream,
                       tt, WT1, b1, dinv, gat, (float*)nullptr, N, 0);

    // layer 2: tt = fp16(dinv.*agg(gat)) ; out = relu(tt@W2+b2)
    hipLaunchKernelGGL(agg_kernel, dim3((N + 3) / 4), dim3(256), 0, stream,
                       gat, rowptr, srcs, ews, dinv, (unsigned*)tt, N);
    hipLaunchKernelGGL(gemm_mfma, dim3(gblocks), dim3(256), 0, stream,
                       tt, WT2, b2, dinv, (_Float16*)nullptr, out, N, 1);
}

// Round 13
// 241.144 us; speedup vs baseline: 1.5673x; 1.1102x over previous
//
#include <hip/hip_runtime.h>
#include <hip/hip_bf16.h>

typedef __attribute__((ext_vector_type(8))) _Float16 half8;
typedef __attribute__((ext_vector_type(4))) float f32x4;
typedef __attribute__((ext_vector_type(4))) float float4v;

#define NPB 256        // nodes per bucket (dst >> 8)
#define PBLK 256       // partition blocks
#define SCAN_TILE 1024

// ---------------- phase 1: per-(block,bucket) histogram ----------------
__global__ __launch_bounds__(256) void p1_hist(const int* __restrict__ dst,
                                               int* __restrict__ MT, int E, int NB, int chunk) {
    __shared__ int h[512];
    int t = threadIdx.x, p = blockIdx.x;
    for (int i = t; i < NB; i += 256) h[i] = 0;
    __syncthreads();
    int beg = p * chunk, end = min(beg + chunk, E);
    for (int e = beg + t; e < end; e += 256) atomicAdd(&h[dst[e] >> 8], 1);
    __syncthreads();
    for (int b = t; b < NB; b += 256) MT[b * PBLK + p] = h[b];
}

// ---------------- device-wide exclusive scan (1024-elem tiles) ----------------
__global__ __launch_bounds__(256) void scanA_kernel(const int* __restrict__ in,
                                                    int* __restrict__ out,
                                                    int* __restrict__ blocksums, int n) {
    __shared__ int sums[256];
    int t = threadIdx.x;
    int base = blockIdx.x * SCAN_TILE + t * 4;
    int v0 = (base + 0 < n) ? in[base + 0] : 0;
    int v1 = (base + 1 < n) ? in[base + 1] : 0;
    int v2 = (base + 2 < n) ? in[base + 2] : 0;
    int v3 = (base + 3 < n) ? in[base + 3] : 0;
    sums[t] = v0 + v1 + v2 + v3;
    __syncthreads();
    for (int off = 1; off < 256; off <<= 1) {
        int add = (t >= off) ? sums[t - off] : 0;
        __syncthreads();
        sums[t] += add;
        __syncthreads();
    }
    int run = (t == 0) ? 0 : sums[t - 1];
    if (base + 0 < n) out[base + 0] = run; run += v0;
    if (base + 1 < n) out[base + 1] = run; run += v1;
    if (base + 2 < n) out[base + 2] = run; run += v2;
    if (base + 3 < n) out[base + 3] = run;
    if (t == 255) blocksums[blockIdx.x] = sums[255];
}

__global__ __launch_bounds__(256) void scanB_kernel(int* __restrict__ blocksums, int nb) {
    __shared__ int sums[256];
    int t = threadIdx.x;
    sums[t] = (t < nb) ? blocksums[t] : 0;
    __syncthreads();
    for (int off = 1; off < 256; off <<= 1) {
        int add = (t >= off) ? sums[t - off] : 0;
        __syncthreads();
        sums[t] += add;
        __syncthreads();
    }
    if (t < nb) blocksums[t] = (t == 0) ? 0 : sums[t - 1];
}

__global__ __launch_bounds__(256) void scanC_kernel(int* __restrict__ data,
                                                    const int* __restrict__ blocksums, int n) {
    int i = blockIdx.x * 256 + threadIdx.x;
    if (i < n) data[i] += blocksums[i / SCAN_TILE];
}

// ---------------- phase 2: partition edges into buckets (LDS cursors only) ----------------
__global__ __launch_bounds__(256) void p2_part(const int* __restrict__ src,
                                               const int* __restrict__ dst,
                                               const float* __restrict__ ew,
                                               const int* __restrict__ MTs,
                                               int* __restrict__ pp, float* __restrict__ pw,
                                               int E, int NB, int chunk) {
    __shared__ int cur[512];
    int t = threadIdx.x, p = blockIdx.x;
    for (int b = t; b < NB; b += 256) cur[b] = MTs[b * PBLK + p];
    __syncthreads();
    int beg = p * chunk, end = min(beg + chunk, E);
    for (int e = beg + t; e < end; e += 256) {
        int d = dst[e];
        int b = d >> 8;
        int pos = atomicAdd(&cur[b], 1);
        pp[pos] = src[e] | ((d & 255) << 20);   // src < 2^20, dlocal in [0,256)
        pw[pos] = ew[e];
    }
}

// ---------------- phase 3: per-bucket exact CSR + degree + dinv ----------------
__global__ __launch_bounds__(256) void p3_bucket(const int* __restrict__ pp,
                                                 const float* __restrict__ pw,
                                                 const int* __restrict__ MTs,
                                                 int* __restrict__ srcs,
                                                 float* __restrict__ ews,
                                                 int* __restrict__ rowptr,
                                                 float* __restrict__ dinv,
                                                 int E, int N, int NB) {
    __shared__ int cnt[256];
    __shared__ float wd[256];
    __shared__ int ls[256];
    __shared__ int cur[256];
    int t = threadIdx.x, b = blockIdx.x;
    int beg = MTs[b * PBLK];
    int end = (b == NB - 1) ? E : MTs[(b + 1) * PBLK];
    cnt[t] = 0;
    wd[t] = 0.0f;
    __syncthreads();
    for (int e = beg + t; e < end; e += 256) {
        int v = pp[e];
        int dl = v >> 20;
        atomicAdd(&cnt[dl], 1);
        atomicAdd(&wd[dl], pw[e]);
    }
    __syncthreads();
    ls[t] = cnt[t];
    __syncthreads();
    for (int off = 1; off < 256; off <<= 1) {
        int add = (t >= off) ? ls[t - off] : 0;
        __syncthreads();
        ls[t] += add;
        __syncthreads();
    }
    int excl = (t == 0) ? 0 : ls[t - 1];
    int node = b * NPB + t;
    if (node < N) {
        rowptr[node] = beg + excl;
        dinv[node] = rsqrtf(1.0f + wd[t]);   // +1 = self-loop weight
    }
    cur[t] = beg + excl;
    if (b == NB - 1 && t == 0) rowptr[N] = E;
    __syncthreads();
    for (int e = beg + t; e < end; e += 256) {
        int v = pp[e];
        int dl = v >> 20;
        int pos = atomicAdd(&cur[dl], 1);
        srcs[pos] = v & 0xFFFFF;
        ews[pos] = pw[e];
    }
}

// ---------------- split_scale: xs = fp16(dinv .* x) ----------------
__global__ __launch_bounds__(256) void split_scale(const float* __restrict__ x,
                                                   const float* __restrict__ dinv,
                                                   _Float16* __restrict__ xs,
                                                   int nquad) {   // nquad = N*32 float4s
    int i = blockIdx.x * 256 + threadIdx.x;
    if (i >= nquad) return;
    float4v v = ((const float4v*)x)[i];
    float s = dinv[i >> 5];   // 32 float4s per 128-col row
    union { uint2 u; _Float16 h[4]; } o;
    o.h[0] = (_Float16)(s * v[0]);
    o.h[1] = (_Float16)(s * v[1]);
    o.h[2] = (_Float16)(s * v[2]);
    o.h[3] = (_Float16)(s * v[3]);
    ((uint2*)xs)[i] = o.u;
}

// ---------------- aggregation v2: 2 independent node streams per wave ----------------
// t = fp16(dinv.*(sum ew*F[src] + F[self])). Batch-interleaved issue doubles the
// outstanding gathers per wave (16 x 256B in flight).
__global__ __launch_bounds__(256) void agg_kernel(const _Float16* __restrict__ F,
                                                  const int* __restrict__ rowptr,
                                                  const int* __restrict__ srcs,
                                                  const float* __restrict__ ews,
                                                  const float* __restrict__ dinv,
                                                  unsigned* __restrict__ ttU, int n) {
    const unsigned* Fu = (const unsigned*)F;   // one uint = 2 fp16 cols
    int wid  = (blockIdx.x * 256 + threadIdx.x) >> 6;
    int lane = threadIdx.x & 63;
    int n0 = __builtin_amdgcn_readfirstlane(wid) * 2;
    if (n0 >= n) return;
    const bool has1 = (n0 + 1) < n;

    int beg0 = rowptr[n0];
    int end0 = rowptr[n0 + 1];
    int end1 = has1 ? rowptr[n0 + 2] : end0;
    float di0 = dinv[n0];
    float di1 = has1 ? dinv[n0 + 1] : 0.0f;

    union { unsigned u; _Float16 h[2]; } cv;
    cv.u = Fu[(size_t)n0 * 64 + lane];
    float a0x = (float)cv.h[0], a0y = (float)cv.h[1];
    float a1x = 0.0f, a1y = 0.0f;
    if (has1) {
        cv.u = Fu[(size_t)(n0 + 1) * 64 + lane];
        a1x = (float)cv.h[0];
        a1y = (float)cv.h[1];
    }

    int e0 = beg0, e1 = end0;

    // paired batches: 16 gathers in flight
    while (e0 + 8 <= end0 && e1 + 8 <= end1) {
        int sA[8], sB[8];
        float wA[8], wB[8];
        unsigned vA[8], vB[8];
#pragma unroll
        for (int j = 0; j < 8; ++j) sA[j] = srcs[e0 + j];
#pragma unroll
        for (int j = 0; j < 8; ++j) sB[j] = srcs[e1 + j];
#pragma unroll
        for (int j = 0; j < 8; ++j) wA[j] = ews[e0 + j];
#pragma unroll
        for (int j = 0; j < 8; ++j) wB[j] = ews[e1 + j];
#pragma unroll
        for (int j = 0; j < 8; ++j) vA[j] = Fu[(size_t)sA[j] * 64 + lane];
#pragma unroll
        for (int j = 0; j < 8; ++j) vB[j] = Fu[(size_t)sB[j] * 64 + lane];
#pragma unroll
        for (int j = 0; j < 8; ++j) {
            cv.u = vA[j];
            a0x += wA[j] * (float)cv.h[0];
            a0y += wA[j] * (float)cv.h[1];
        }
#pragma unroll
        for (int j = 0; j < 8; ++j) {
            cv.u = vB[j];
            a1x += wB[j] * (float)cv.h[0];
            a1y += wB[j] * (float)cv.h[1];
        }
        e0 += 8;
        e1 += 8;
    }
    // drain stream 0
    for (; e0 + 8 <= end0; e0 += 8) {
        int s_[8]; float w_[8]; unsigned v_[8];
#pragma unroll
        for (int j = 0; j < 8; ++j) s_[j] = srcs[e0 + j];
#pragma unroll
        for (int j = 0; j < 8; ++j) w_[j] = ews[e0 + j];
#pragma unroll
        for (int j = 0; j < 8; ++j) v_[j] = Fu[(size_t)s_[j] * 64 + lane];
#pragma unroll
        for (int j = 0; j < 8; ++j) {
            cv.u = v_[j];
            a0x += w_[j] * (float)cv.h[0];
            a0y += w_[j] * (float)cv.h[1];
        }
    }
    // drain stream 1
    for (; e1 + 8 <= end1; e1 += 8) {
        int s_[8]; float w_[8]; unsigned v_[8];
#pragma unroll
        for (int j = 0; j < 8; ++j) s_[j] = srcs[e1 + j];
#pragma unroll
        for (int j = 0; j < 8; ++j) w_[j] = ews[e1 + j];
#pragma unroll
        for (int j = 0; j < 8; ++j) v_[j] = Fu[(size_t)s_[j] * 64 + lane];
#pragma unroll
        for (int j = 0; j < 8; ++j) {
            cv.u = v_[j];
            a1x += w_[j] * (float)cv.h[0];
            a1y += w_[j] * (float)cv.h[1];
        }
    }
    // scalar tails
    for (; e0 < end0; ++e0) {
        float w = ews[e0];
        cv.u = Fu[(size_t)srcs[e0] * 64 + lane];
        a0x += w * (float)cv.h[0];
        a0y += w * (float)cv.h[1];
    }
    for (; e1 < end1; ++e1) {
        float w = ews[e1];
        cv.u = Fu[(size_t)srcs[e1] * 64 + lane];
        a1x += w * (float)cv.h[0];
        a1y += w * (float)cv.h[1];
    }

    union { unsigned u; _Float16 h[2]; } o;
    o.h[0] = (_Float16)(di0 * a0x);
    o.h[1] = (_Float16)(di0 * a0y);
    ttU[(size_t)n0 * 64 + lane] = o.u;
    if (has1) {
        o.h[0] = (_Float16)(di1 * a1x);
        o.h[1] = (_Float16)(di1 * a1y);
        ttU[(size_t)(n0 + 1) * 64 + lane] = o.u;
    }
}

// ---------------- MFMA GEMM (fp16, LDS-staged W): out = relu(A @ W + b) ----------------
// A fp16 single plane; W staged fp16 in LDS (32 KB, transposed+swizzled).
// 32-row wave panels (one per wave), acc 64 VGPR, 3 blocks/CU.
// mode 0: outb = fp16(dinv .* relu(..));  mode 1: outf = relu(..)
__global__ __launch_bounds__(256, 3) void gemm_mfma(const _Float16* __restrict__ A,
                                                    const float* __restrict__ W,
                                                    const float* __restrict__ bias,
                                                    const float* __restrict__ dinv,
                                                    _Float16* __restrict__ outb,
                                                    float* __restrict__ outf,
                                                    int nrows, int mode) {
    __shared__ _Float16 sW[128 * 128];   // [c][k], swizzled

    const int t = threadIdx.x;

    // ---- stage W transposed [c][k]: coalesced reads, b128 LDS writes ----
    {
        const int c = t & 127;
        const int kg0 = t >> 7;   // 0..1
#pragma unroll
        for (int it = 0; it < 8; ++it) {
            int kg = kg0 + it * 2;   // 0..15
            half8 h8;
#pragma unroll
            for (int j = 0; j < 8; ++j)
                h8[j] = (_Float16)W[(size_t)(kg * 8 + j) * 128 + c];
            int idx = (c * 128 + kg * 8) ^ ((c & 7) << 3);
            *(half8*)&sW[idx] = h8;
        }
    }
    __syncthreads();   // the only barrier

    const int lane = t & 63;
    const int fr = lane & 15;      // frag row/col index
    const int kq = lane >> 4;      // 0..3 -> k sub-offset 8*kq

    const int wid = blockIdx.x * 4 + (t >> 6);      // one 32-row panel per wave
    const int npan = (nrows + 31) >> 5;
    if (wid >= npan) return;
    const int r0 = wid * 32;

    float bv[8];
#pragma unroll
    for (int fc = 0; fc < 8; ++fc) bv[fc] = bias[fc * 16 + fr];

    const half8 z8 = {0, 0, 0, 0, 0, 0, 0, 0};

#define LOADA(KS, AH)                                                         \
    {                                                                         \
        _Pragma("unroll")                                                     \
        for (int rf_ = 0; rf_ < 2; ++rf_) {                                   \
            int row_ = r0 + rf_ * 16 + fr;                                    \
            if (row_ < nrows) {                                               \
                AH[rf_] = *(const half8*)(A + (size_t)row_ * 128 + (KS) * 32 + kq * 8); \
            } else {                                                          \
                AH[rf_] = z8;                                                 \
            }                                                                 \
        }                                                                     \
    }

#define KSTEP(KS, AH)                                                         \
    {                                                                         \
        _Pragma("unroll")                                                     \
        for (int fc_ = 0; fc_ < 8; ++fc_) {                                   \
            int c_ = fc_ * 16 + fr;                                           \
            int bidx_ = (c_ * 128 + (KS) * 32 + kq * 8) ^ ((c_ & 7) << 3);    \
            half8 b_ = *(half8*)&sW[bidx_];                                   \
            _Pragma("unroll")                                                 \
            for (int rf_ = 0; rf_ < 2; ++rf_) {                               \
                acc[rf_][fc_] = __builtin_amdgcn_mfma_f32_16x16x32_f16(       \
                    AH[rf_], b_, acc[rf_][fc_], 0, 0, 0);                     \
            }                                                                 \
        }                                                                     \
    }

    f32x4 acc[2][8];
#pragma unroll
    for (int rf = 0; rf < 2; ++rf)
#pragma unroll
        for (int fc = 0; fc < 8; ++fc) acc[rf][fc] = (f32x4){0.f, 0.f, 0.f, 0.f};

    half8 aA[2], aB[2];
    LOADA(0, aA);
    LOADA(1, aB);
    KSTEP(0, aA);
    LOADA(2, aA);
    KSTEP(1, aB);
    LOADA(3, aB);
    KSTEP(2, aA);
    KSTEP(3, aB);

#undef LOADA
#undef KSTEP

    // ---- epilogue: relu + bias; mode 0 -> dinv-scaled fp16, mode 1 -> fp32 ----
    if (mode == 0) {
#pragma unroll
        for (int rf = 0; rf < 2; ++rf) {
            int rb = r0 + rf * 16 + kq * 4;
#pragma unroll
            for (int r = 0; r < 4; ++r) {
                int grow = rb + r;
                if (grow < nrows) {
                    float s = dinv[grow];
#pragma unroll
                    for (int fc = 0; fc < 8; ++fc) {
                        float v = fmaxf(acc[rf][fc][r] + bv[fc], 0.0f);
                        outb[(size_t)grow * 128 + fc * 16 + fr] = (_Float16)(s * v);
                    }
                }
            }
        }
    } else {
#pragma unroll
        for (int rf = 0; rf < 2; ++rf) {
            int rb = r0 + rf * 16 + kq * 4;
#pragma unroll
            for (int r = 0; r < 4; ++r) {
                int grow = rb + r;
                if (grow < nrows) {
#pragma unroll
                    for (int fc = 0; fc < 8; ++fc) {
                        outf[(size_t)grow * 128 + fc * 16 + fr] =
                            fmaxf(acc[rf][fc][r] + bv[fc], 0.0f);
                    }
                }
            }
        }
    }
}

// ---------------- launcher ----------------

extern "C" void kernel_launch(void* const* d_in, const int* in_sizes, int n_in,
                              void* d_out, int out_size, void* d_ws, size_t ws_size,
                              hipStream_t stream) {
    const float* x  = (const float*)d_in[0];
    const int*   ei = (const int*)d_in[1];
    const float* ew = (const float*)d_in[2];
    const float* W1 = (const float*)d_in[3];
    const float* b1 = (const float*)d_in[4];
    const float* W2 = (const float*)d_in[5];
    const float* b2 = (const float*)d_in[6];
    float* out = (float*)d_out;

    const int N = in_sizes[0] / 128;
    const int E = in_sizes[2];
    const int* src = ei;
    const int* dst = ei + E;

    const int NB = (N + NPB - 1) / NPB;        // buckets (391 for N=100k)
    const int L  = NB * PBLK;                  // count-matrix length
    const int chunk = (E + PBLK - 1) / PBLK;

    // workspace layout
    _Float16* gat = (_Float16*)d_ws;                      // N*128 fp16 (gather features)
    _Float16* tt  = gat + (size_t)N * 128;                // N*128 fp16 (agg result t)
    int*   srcs   = (int*)(tt + (size_t)N * 128);         // E
    float* ews    = (float*)(srcs + E);        // E
    int*   rowptr = (int*)(ews + E);           // N+1
    float* dinv   = (float*)(rowptr + N + 1);  // N
    int*   MT     = (int*)(dinv + N);          // L
    int*   MTs    = MT + L;                    // L
    int*   bsums  = MTs + L;                   // ceil(L/1024)
    int*   pp     = (int*)gat;                 // alias (E ints, dead before gat written)
    float* pw     = (float*)tt;                // alias (E floats, dead before tt written)

    const int nb_scan = (L + SCAN_TILE - 1) / SCAN_TILE;
    const int npan = (N + 31) / 32;
    const int gblocks = (npan + 3) / 4;
    const int ablocks = (N + 7) / 8;           // 4 waves/block x 2 nodes/wave

    hipLaunchKernelGGL(p1_hist, dim3(PBLK), dim3(256), 0, stream, dst, MT, E, NB, chunk);
    hipLaunchKernelGGL(scanA_kernel, dim3(nb_scan), dim3(256), 0, stream, MT, MTs, bsums, L);
    hipLaunchKernelGGL(scanB_kernel, dim3(1), dim3(256), 0, stream, bsums, nb_scan);
    hipLaunchKernelGGL(scanC_kernel, dim3((L + 255) / 256), dim3(256), 0, stream, MTs, bsums, L);
    hipLaunchKernelGGL(p2_part, dim3(PBLK), dim3(256), 0, stream, src, dst, ew, MTs, pp, pw, E, NB, chunk);
    hipLaunchKernelGGL(p3_bucket, dim3(NB), dim3(256), 0, stream, pp, pw, MTs, srcs, ews, rowptr, dinv, E, N, NB);

    // gat = fp16(dinv .* x)
    hipLaunchKernelGGL(split_scale, dim3((N * 32 + 255) / 256), dim3(256), 0, stream,
                       x, dinv, gat, N * 32);

    // layer 1: tt = fp16(dinv.*agg(gat)) ; gat = fp16(dinv.*relu(tt@W1+b1))
    hipLaunchKernelGGL(agg_kernel, dim3(ablocks), dim3(256), 0, stream,
                       gat, rowptr, srcs, ews, dinv, (unsigned*)tt, N);
    hipLaunchKernelGGL(gemm_mfma, dim3(gblocks), dim3(256), 0, stream,
                       tt, W1, b1, dinv, gat, (float*)nullptr, N, 0);

    // layer 2: tt = fp16(dinv.*agg(gat)) ; out = relu(tt@W2+b2)
    hipLaunchKernelGGL(agg_kernel, dim3(ablocks), dim3(256), 0, stream,
                       gat, rowptr, srcs, ews, dinv, (unsigned*)tt, N);
    hipLaunchKernelGGL(gemm_mfma, dim3(gblocks), dim3(256), 0, stream,
                       tt, W2, b2, dinv, (_Float16*)nullptr, out, N, 1);
}

// Round 14
// 235.843 us; speedup vs baseline: 1.6025x; 1.0225x over previous
//
#include <hip/hip_runtime.h>
#include <hip/hip_bf16.h>

typedef __attribute__((ext_vector_type(8))) _Float16 half8;
typedef __attribute__((ext_vector_type(4))) float f32x4;
typedef __attribute__((ext_vector_type(4))) float float4v;

#define NPB 256        // nodes per bucket (dst >> 8)
#define PBLK 256       // partition blocks
#define SCAN_TILE 1024

// ---------------- phase 1: per-(block,bucket) histogram ----------------
__global__ __launch_bounds__(256) void p1_hist(const int* __restrict__ dst,
                                               int* __restrict__ MT, int E, int NB, int chunk) {
    __shared__ int h[512];
    int t = threadIdx.x, p = blockIdx.x;
    for (int i = t; i < NB; i += 256) h[i] = 0;
    __syncthreads();
    int beg = p * chunk, end = min(beg + chunk, E);
    for (int e = beg + t; e < end; e += 256) atomicAdd(&h[dst[e] >> 8], 1);
    __syncthreads();
    for (int b = t; b < NB; b += 256) MT[b * PBLK + p] = h[b];
}

// ---------------- device-wide exclusive scan (1024-elem tiles) ----------------
__global__ __launch_bounds__(256) void scanA_kernel(const int* __restrict__ in,
                                                    int* __restrict__ out,
                                                    int* __restrict__ blocksums, int n) {
    __shared__ int sums[256];
    int t = threadIdx.x;
    int base = blockIdx.x * SCAN_TILE + t * 4;
    int v0 = (base + 0 < n) ? in[base + 0] : 0;
    int v1 = (base + 1 < n) ? in[base + 1] : 0;
    int v2 = (base + 2 < n) ? in[base + 2] : 0;
    int v3 = (base + 3 < n) ? in[base + 3] : 0;
    sums[t] = v0 + v1 + v2 + v3;
    __syncthreads();
    for (int off = 1; off < 256; off <<= 1) {
        int add = (t >= off) ? sums[t - off] : 0;
        __syncthreads();
        sums[t] += add;
        __syncthreads();
    }
    int run = (t == 0) ? 0 : sums[t - 1];
    if (base + 0 < n) out[base + 0] = run; run += v0;
    if (base + 1 < n) out[base + 1] = run; run += v1;
    if (base + 2 < n) out[base + 2] = run; run += v2;
    if (base + 3 < n) out[base + 3] = run;
    if (t == 255) blocksums[blockIdx.x] = sums[255];
}

__global__ __launch_bounds__(256) void scanB_kernel(int* __restrict__ blocksums, int nb) {
    __shared__ int sums[256];
    int t = threadIdx.x;
    sums[t] = (t < nb) ? blocksums[t] : 0;
    __syncthreads();
    for (int off = 1; off < 256; off <<= 1) {
        int add = (t >= off) ? sums[t - off] : 0;
        __syncthreads();
        sums[t] += add;
        __syncthreads();
    }
    if (t < nb) blocksums[t] = (t == 0) ? 0 : sums[t - 1];
}

__global__ __launch_bounds__(256) void scanC_kernel(int* __restrict__ data,
                                                    const int* __restrict__ blocksums, int n) {
    int i = blockIdx.x * 256 + threadIdx.x;
    if (i < n) data[i] += blocksums[i / SCAN_TILE];
}

// ---------------- phase 2: partition edges into buckets (LDS cursors only) ----------------
// edge record = uint2{ src | dlocal<<20, bits(ew) } — single 8B scattered store
__global__ __launch_bounds__(256) void p2_part(const int* __restrict__ src,
                                               const int* __restrict__ dst,
                                               const float* __restrict__ ew,
                                               const int* __restrict__ MTs,
                                               uint2* __restrict__ edg,
                                               int E, int NB, int chunk) {
    __shared__ int cur[512];
    int t = threadIdx.x, p = blockIdx.x;
    for (int b = t; b < NB; b += 256) cur[b] = MTs[b * PBLK + p];
    __syncthreads();
    int beg = p * chunk, end = min(beg + chunk, E);
    for (int e = beg + t; e < end; e += 256) {
        int d = dst[e];
        int b = d >> 8;
        int pos = atomicAdd(&cur[b], 1);
        uint2 rec;
        rec.x = (unsigned)src[e] | ((unsigned)(d & 255) << 20);
        rec.y = __float_as_uint(ew[e]);
        edg[pos] = rec;
    }
}

// ---------------- phase 3: per-bucket exact CSR + degree + dinv ----------------
__global__ __launch_bounds__(256) void p3_bucket(const uint2* __restrict__ edg,
                                                 const int* __restrict__ MTs,
                                                 uint2* __restrict__ edgf,
                                                 int* __restrict__ rowptr,
                                                 float* __restrict__ dinv,
                                                 int E, int N, int NB) {
    __shared__ int cnt[256];
    __shared__ float wd[256];
    __shared__ int ls[256];
    __shared__ int cur[256];
    int t = threadIdx.x, b = blockIdx.x;
    int beg = MTs[b * PBLK];
    int end = (b == NB - 1) ? E : MTs[(b + 1) * PBLK];
    cnt[t] = 0;
    wd[t] = 0.0f;
    __syncthreads();
    for (int e = beg + t; e < end; e += 256) {
        uint2 v = edg[e];
        int dl = v.x >> 20;
        atomicAdd(&cnt[dl], 1);
        atomicAdd(&wd[dl], __uint_as_float(v.y));
    }
    __syncthreads();
    ls[t] = cnt[t];
    __syncthreads();
    for (int off = 1; off < 256; off <<= 1) {
        int add = (t >= off) ? ls[t - off] : 0;
        __syncthreads();
        ls[t] += add;
        __syncthreads();
    }
    int excl = (t == 0) ? 0 : ls[t - 1];
    int node = b * NPB + t;
    if (node < N) {
        rowptr[node] = beg + excl;
        dinv[node] = rsqrtf(1.0f + wd[t]);   // +1 = self-loop weight
    }
    cur[t] = beg + excl;
    if (b == NB - 1 && t == 0) rowptr[N] = E;
    __syncthreads();
    for (int e = beg + t; e < end; e += 256) {
        uint2 v = edg[e];
        int dl = v.x >> 20;
        int pos = atomicAdd(&cur[dl], 1);
        uint2 rec;
        rec.x = v.x & 0xFFFFF;
        rec.y = v.y;
        edgf[pos] = rec;
    }
}

// ---------------- split_scale: xs = fp16(dinv .* x) ----------------
__global__ __launch_bounds__(256) void split_scale(const float* __restrict__ x,
                                                   const float* __restrict__ dinv,
                                                   _Float16* __restrict__ xs,
                                                   int nquad) {   // nquad = N*32 float4s
    int i = blockIdx.x * 256 + threadIdx.x;
    if (i >= nquad) return;
    float4v v = ((const float4v*)x)[i];
    float s = dinv[i >> 5];   // 32 float4s per 128-col row
    union { uint2 u; _Float16 h[4]; } o;
    o.h[0] = (_Float16)(s * v[0]);
    o.h[1] = (_Float16)(s * v[1]);
    o.h[2] = (_Float16)(s * v[2]);
    o.h[3] = (_Float16)(s * v[3]);
    ((uint2*)xs)[i] = o.u;
}

// ---------------- aggregation: 2 independent node streams per wave ----------------
// t = fp16(dinv.*(sum ew*F[src] + F[self])); edges as interleaved uint2 records.
__global__ __launch_bounds__(256) void agg_kernel(const _Float16* __restrict__ F,
                                                  const int* __restrict__ rowptr,
                                                  const uint2* __restrict__ edg,
                                                  const float* __restrict__ dinv,
                                                  unsigned* __restrict__ ttU, int n) {
    const unsigned* Fu = (const unsigned*)F;   // one uint = 2 fp16 cols
    int wid  = (blockIdx.x * 256 + threadIdx.x) >> 6;
    int lane = threadIdx.x & 63;
    int n0 = __builtin_amdgcn_readfirstlane(wid) * 2;
    if (n0 >= n) return;
    const bool has1 = (n0 + 1) < n;

    int beg0 = rowptr[n0];
    int end0 = rowptr[n0 + 1];
    int end1 = has1 ? rowptr[n0 + 2] : end0;
    float di0 = dinv[n0];
    float di1 = has1 ? dinv[n0 + 1] : 0.0f;

    union { unsigned u; _Float16 h[2]; } cv;
    cv.u = Fu[(size_t)n0 * 64 + lane];
    float a0x = (float)cv.h[0], a0y = (float)cv.h[1];
    float a1x = 0.0f, a1y = 0.0f;
    if (has1) {
        cv.u = Fu[(size_t)(n0 + 1) * 64 + lane];
        a1x = (float)cv.h[0];
        a1y = (float)cv.h[1];
    }

    int e0 = beg0, e1 = end0;

    while (e0 + 8 <= end0 && e1 + 8 <= end1) {
        uint2 rA[8], rB[8];
        unsigned vA[8], vB[8];
#pragma unroll
        for (int j = 0; j < 8; ++j) rA[j] = edg[e0 + j];
#pragma unroll
        for (int j = 0; j < 8; ++j) rB[j] = edg[e1 + j];
#pragma unroll
        for (int j = 0; j < 8; ++j) vA[j] = Fu[(size_t)rA[j].x * 64 + lane];
#pragma unroll
        for (int j = 0; j < 8; ++j) vB[j] = Fu[(size_t)rB[j].x * 64 + lane];
#pragma unroll
        for (int j = 0; j < 8; ++j) {
            float w = __uint_as_float(rA[j].y);
            cv.u = vA[j];
            a0x += w * (float)cv.h[0];
            a0y += w * (float)cv.h[1];
        }
#pragma unroll
        for (int j = 0; j < 8; ++j) {
            float w = __uint_as_float(rB[j].y);
            cv.u = vB[j];
            a1x += w * (float)cv.h[0];
            a1y += w * (float)cv.h[1];
        }
        e0 += 8;
        e1 += 8;
    }
    for (; e0 + 8 <= end0; e0 += 8) {
        uint2 r_[8];
        unsigned v_[8];
#pragma unroll
        for (int j = 0; j < 8; ++j) r_[j] = edg[e0 + j];
#pragma unroll
        for (int j = 0; j < 8; ++j) v_[j] = Fu[(size_t)r_[j].x * 64 + lane];
#pragma unroll
        for (int j = 0; j < 8; ++j) {
            float w = __uint_as_float(r_[j].y);
            cv.u = v_[j];
            a0x += w * (float)cv.h[0];
            a0y += w * (float)cv.h[1];
        }
    }
    for (; e1 + 8 <= end1; e1 += 8) {
        uint2 r_[8];
        unsigned v_[8];
#pragma unroll
        for (int j = 0; j < 8; ++j) r_[j] = edg[e1 + j];
#pragma unroll
        for (int j = 0; j < 8; ++j) v_[j] = Fu[(size_t)r_[j].x * 64 + lane];
#pragma unroll
        for (int j = 0; j < 8; ++j) {
            float w = __uint_as_float(r_[j].y);
            cv.u = v_[j];
            a1x += w * (float)cv.h[0];
            a1y += w * (float)cv.h[1];
        }
    }
    for (; e0 < end0; ++e0) {
        uint2 r = edg[e0];
        float w = __uint_as_float(r.y);
        cv.u = Fu[(size_t)r.x * 64 + lane];
        a0x += w * (float)cv.h[0];
        a0y += w * (float)cv.h[1];
    }
    for (; e1 < end1; ++e1) {
        uint2 r = edg[e1];
        float w = __uint_as_float(r.y);
        cv.u = Fu[(size_t)r.x * 64 + lane];
        a1x += w * (float)cv.h[0];
        a1y += w * (float)cv.h[1];
    }

    union { unsigned u; _Float16 h[2]; } o;
    o.h[0] = (_Float16)(di0 * a0x);
    o.h[1] = (_Float16)(di0 * a0y);
    ttU[(size_t)n0 * 64 + lane] = o.u;
    if (has1) {
        o.h[0] = (_Float16)(di1 * a1x);
        o.h[1] = (_Float16)(di1 * a1y);
        ttU[(size_t)(n0 + 1) * 64 + lane] = o.u;
    }
}

// ---------------- MFMA GEMM (fp16, LDS-staged W, swapped operands) ----------------
// out = relu(A @ W + b). Operand swap mfma(W_frag, t_frag): D is transposed so each
// lane holds 4 CONSECUTIVE output columns of one row -> packed uint2/float4 stores.
// mode 0: outb = fp16(dinv .* relu(..));  mode 1: outf = relu(..)
__global__ __launch_bounds__(256, 3) void gemm_mfma(const _Float16* __restrict__ A,
                                                    const float* __restrict__ W,
                                                    const float* __restrict__ bias,
                                                    const float* __restrict__ dinv,
                                                    _Float16* __restrict__ outb,
                                                    float* __restrict__ outf,
                                                    int nrows, int mode) {
    __shared__ _Float16 sW[128 * 128];   // [c][k], swizzled

    const int t = threadIdx.x;

    // ---- stage W transposed [c][k]: coalesced reads, b128 LDS writes ----
    {
        const int c = t & 127;
        const int kg0 = t >> 7;   // 0..1
#pragma unroll
        for (int it = 0; it < 8; ++it) {
            int kg = kg0 + it * 2;   // 0..15
            half8 h8;
#pragma unroll
            for (int j = 0; j < 8; ++j)
                h8[j] = (_Float16)W[(size_t)(kg * 8 + j) * 128 + c];
            int idx = (c * 128 + kg * 8) ^ ((c & 7) << 3);
            *(half8*)&sW[idx] = h8;
        }
    }
    __syncthreads();   // the only barrier

    const int lane = t & 63;
    const int fr = lane & 15;      // row index within 16-row block / W-col sub-index
    const int kq = lane >> 4;      // 0..3

    const int wid = blockIdx.x * 4 + (t >> 6);      // one 32-row panel per wave
    const int npan = (nrows + 31) >> 5;
    if (wid >= npan) return;
    const int r0 = wid * 32;

    // bias: 4 consecutive cols per lane per fc
    float4v bv4[8];
#pragma unroll
    for (int fc = 0; fc < 8; ++fc)
        bv4[fc] = *(const float4v*)(bias + fc * 16 + kq * 4);

    const half8 z8 = {0, 0, 0, 0, 0, 0, 0, 0};

#define LOADA(KS, AH)                                                         \
    {                                                                         \
        _Pragma("unroll")                                                     \
        for (int rf_ = 0; rf_ < 2; ++rf_) {                                   \
            int row_ = r0 + rf_ * 16 + fr;                                    \
            if (row_ < nrows) {                                               \
                AH[rf_] = *(const half8*)(A + (size_t)row_ * 128 + (KS) * 32 + kq * 8); \
            } else {                                                          \
                AH[rf_] = z8;                                                 \
            }                                                                 \
        }                                                                     \
    }

// swapped operands: mfma(W_frag, t_frag) -> D[col = t-row(fr), row = W-col(kq*4+reg)]
#define KSTEP(KS, AH)                                                         \
    {                                                                         \
        _Pragma("unroll")                                                     \
        for (int fc_ = 0; fc_ < 8; ++fc_) {                                   \
            int c_ = fc_ * 16 + fr;                                           \
            int bidx_ = (c_ * 128 + (KS) * 32 + kq * 8) ^ ((c_ & 7) << 3);    \
            half8 w_ = *(half8*)&sW[bidx_];                                   \
            _Pragma("unroll")                                                 \
            for (int rf_ = 0; rf_ < 2; ++rf_) {                               \
                acc[rf_][fc_] = __builtin_amdgcn_mfma_f32_16x16x32_f16(       \
                    w_, AH[rf_], acc[rf_][fc_], 0, 0, 0);                     \
            }                                                                 \
        }                                                                     \
    }

    f32x4 acc[2][8];
#pragma unroll
    for (int rf = 0; rf < 2; ++rf)
#pragma unroll
        for (int fc = 0; fc < 8; ++fc) acc[rf][fc] = (f32x4){0.f, 0.f, 0.f, 0.f};

    half8 aA[2], aB[2];
    LOADA(0, aA);
    LOADA(1, aB);
    KSTEP(0, aA);
    LOADA(2, aA);
    KSTEP(1, aB);
    LOADA(3, aB);
    KSTEP(2, aA);
    KSTEP(3, aB);

#undef LOADA
#undef KSTEP

    // ---- epilogue: lane owns row (r0+rf*16+fr), cols fc*16+kq*4 .. +3 ----
    if (mode == 0) {
#pragma unroll
        for (int rf = 0; rf < 2; ++rf) {
            int grow = r0 + rf * 16 + fr;
            if (grow < nrows) {
                float s = dinv[grow];
#pragma unroll
                for (int fc = 0; fc < 8; ++fc) {
                    union { uint2 u; _Float16 h[4]; } o;
#pragma unroll
                    for (int rg = 0; rg < 4; ++rg)
                        o.h[rg] = (_Float16)(s * fmaxf(acc[rf][fc][rg] + bv4[fc][rg], 0.0f));
                    *(uint2*)(outb + (size_t)grow * 128 + fc * 16 + kq * 4) = o.u;
                }
            }
        }
    } else {
#pragma unroll
        for (int rf = 0; rf < 2; ++rf) {
            int grow = r0 + rf * 16 + fr;
            if (grow < nrows) {
#pragma unroll
                for (int fc = 0; fc < 8; ++fc) {
                    float4v o;
#pragma unroll
                    for (int rg = 0; rg < 4; ++rg)
                        o[rg] = fmaxf(acc[rf][fc][rg] + bv4[fc][rg], 0.0f);
                    *(float4v*)(outf + (size_t)grow * 128 + fc * 16 + kq * 4) = o;
                }
            }
        }
    }
}

// ---------------- launcher ----------------

extern "C" void kernel_launch(void* const* d_in, const int* in_sizes, int n_in,
                              void* d_out, int out_size, void* d_ws, size_t ws_size,
                              hipStream_t stream) {
    const float* x  = (const float*)d_in[0];
    const int*   ei = (const int*)d_in[1];
    const float* ew = (const float*)d_in[2];
    const float* W1 = (const float*)d_in[3];
    const float* b1 = (const float*)d_in[4];
    const float* W2 = (const float*)d_in[5];
    const float* b2 = (const float*)d_in[6];
    float* out = (float*)d_out;

    const int N = in_sizes[0] / 128;
    const int E = in_sizes[2];
    const int* src = ei;
    const int* dst = ei + E;

    const int NB = (N + NPB - 1) / NPB;        // buckets (391 for N=100k)
    const int L  = NB * PBLK;                  // count-matrix length
    const int chunk = (E + PBLK - 1) / PBLK;

    // workspace layout
    _Float16* gat  = (_Float16*)d_ws;                     // N*128 fp16 (gather features)
    _Float16* tt   = gat + (size_t)N * 128;               // N*128 fp16 (agg result t)
    uint2*   edgf  = (uint2*)(tt + (size_t)N * 128);      // E (final CSR edge records)
    int*   rowptr  = (int*)(edgf + E);         // N+1
    float* dinv    = (float*)(rowptr + N + 1); // N
    int*   MT      = (int*)(dinv + N);         // L
    int*   MTs     = MT + L;                   // L
    int*   bsums   = MTs + L;                  // ceil(L/1024)
    uint2* edg     = (uint2*)gat;              // alias (E uint2 = 12.8 MB < 25.6 MB, dead before gat written)

    const int nb_scan = (L + SCAN_TILE - 1) / SCAN_TILE;
    const int npan = (N + 31) / 32;
    const int gblocks = (npan + 3) / 4;
    const int ablocks = (N + 7) / 8;           // 4 waves/block x 2 nodes/wave

    hipLaunchKernelGGL(p1_hist, dim3(PBLK), dim3(256), 0, stream, dst, MT, E, NB, chunk);
    hipLaunchKernelGGL(scanA_kernel, dim3(nb_scan), dim3(256), 0, stream, MT, MTs, bsums, L);
    hipLaunchKernelGGL(scanB_kernel, dim3(1), dim3(256), 0, stream, bsums, nb_scan);
    hipLaunchKernelGGL(scanC_kernel, dim3((L + 255) / 256), dim3(256), 0, stream, MTs, bsums, L);
    hipLaunchKernelGGL(p2_part, dim3(PBLK), dim3(256), 0, stream, src, dst, ew, MTs, edg, E, NB, chunk);
    hipLaunchKernelGGL(p3_bucket, dim3(NB), dim3(256), 0, stream, edg, MTs, edgf, rowptr, dinv, E, N, NB);

    // gat = fp16(dinv .* x)   (overwrites edg alias — edg dead after p3)
    hipLaunchKernelGGL(split_scale, dim3((N * 32 + 255) / 256), dim3(256), 0, stream,
                       x, dinv, gat, N * 32);

    // layer 1: tt = fp16(dinv.*agg(gat)) ; gat = fp16(dinv.*relu(tt@W1+b1))
    hipLaunchKernelGGL(agg_kernel, dim3(ablocks), dim3(256), 0, stream,
                       gat, rowptr, edgf, dinv, (unsigned*)tt, N);
    hipLaunchKernelGGL(gemm_mfma, dim3(gblocks), dim3(256), 0, stream,
                       tt, W1, b1, dinv, gat, (float*)nullptr, N, 0);

    // layer 2: tt = fp16(dinv.*agg(gat)) ; out = relu(tt@W2+b2)
    hipLaunchKernelGGL(agg_kernel, dim3(ablocks), dim3(256), 0, stream,
                       gat, rowptr, edgf, dinv, (unsigned*)tt, N);
    hipLaunchKernelGGL(gemm_mfma, dim3(gblocks), dim3(256), 0, stream,
                       tt, W2, b2, dinv, (_Float16*)nullptr, out, N, 1);
}